// Round 9
// baseline (298.170 us; speedup 1.0000x reference)
//
#include <hip/hip_runtime.h>

#define B_ 32
#define K_ 1024
#define F_ 128
#define E_ 128
#define OUT2_ 125
#define ALPHA_ 0.2f

typedef __bf16 bf16x8_t __attribute__((ext_vector_type(8)));
typedef float  f32x4_t  __attribute__((ext_vector_type(4)));

// ------- x transpose+cvt + scores + (fused) prep ----------------------------
__global__ __launch_bounds__(256) void k_xts(const float* __restrict__ x,
                                             const float* __restrict__ lin_w,
                                             const float* __restrict__ lin_b,
                                             const float* __restrict__ a,
                                             unsigned short* __restrict__ xt,
                                             float* __restrict__ s1,
                                             float* __restrict__ s2) {
    int kt = blockIdx.x;
    int b  = blockIdx.y;
    int t  = threadIdx.x;
    __shared__ float xs[64 * 132];
    __shared__ float red1[4][64], red2[4][64];
    __shared__ float wsl[260];

    // ws: waves 0-1 -> a1 path (f = t), waves 2-3 -> a2 path
    {
        int f = t & 127, sel = t >> 7;
        const float* av = a + sel * 128;
        float acc = 0.f;
#pragma unroll 8
        for (int e = 0; e < E_; ++e) acc += lin_w[e * F_ + f] * av[e];
        wsl[sel * 128 + f] = acc;
        if (t < 2) {
            const float* aw = a + t * 128;
            float c = 0.f;
#pragma unroll 8
            for (int e = 0; e < E_; ++e) c += lin_b[e] * aw[e];
            wsl[256 + t] = c;
        }
    }
    const float* xb = x + ((size_t)b * K_ + kt * 64) * F_;
#pragma unroll
    for (int q = 0; q < 8; ++q) {
        int flat = q * 256 + t;
        int kk = flat >> 5, f4 = flat & 31;
        float4 v = *(const float4*)(xb + (size_t)kk * F_ + f4 * 4);
        xs[kk * 132 + f4 * 4]     = v.x;
        xs[kk * 132 + f4 * 4 + 1] = v.y;
        xs[kk * 132 + f4 * 4 + 2] = v.z;
        xs[kk * 132 + f4 * 4 + 3] = v.w;
    }
    __syncthreads();
    // transpose-pack (bf16) — native casts
    {
        int f = t >> 1, half = t & 1;
        union { __bf16 h[32]; uint4 v[4]; } pack;
#pragma unroll
        for (int i = 0; i < 32; ++i) pack.h[i] = (__bf16)xs[(half * 32 + i) * 132 + f];
        unsigned short* dst = xt + (((size_t)(b * 16 + kt) * 128 + f) * 64 + half * 32);
        uint4* d4 = (uint4*)dst;
#pragma unroll
        for (int i = 0; i < 4; ++i) d4[i] = pack.v[i];
    }
    // scores: row r = t&63, f-segment p = t>>6 (32 f each), reduce via LDS
    {
        int r = t & 63, p = t >> 6;
        const float4* xr = (const float4*)&xs[r * 132 + p * 32];
        const float4* w1 = (const float4*)&wsl[p * 32];
        const float4* w2 = (const float4*)&wsl[128 + p * 32];
        float a1 = 0.f, a2 = 0.f;
#pragma unroll
        for (int q = 0; q < 8; ++q) {
            float4 xv = xr[q];
            float4 wa = w1[q], wb = w2[q];
            a1 += xv.x * wa.x + xv.y * wa.y + xv.z * wa.z + xv.w * wa.w;
            a2 += xv.x * wb.x + xv.y * wb.y + xv.z * wb.z + xv.w * wb.w;
        }
        red1[p][r] = a1; red2[p][r] = a2;
    }
    __syncthreads();
    if (t < 64) {
        s1[(size_t)b * K_ + kt * 64 + t] =
            red1[0][t] + red1[1][t] + red1[2][t] + red1[3][t] + wsl[256];
    } else if (t < 128) {
        int r = t - 64;
        s2[(size_t)b * K_ + kt * 64 + r] =
            red2[0][r] + red2[1][r] + red2[2][r] + red2[3][r] + wsl[257];
    }
}

// ---------------- softmax: one block per (i,b) row, no max pass --------------
__global__ __launch_bounds__(256) void k_softmax(const float* __restrict__ s1,
                                                 const float* __restrict__ s2,
                                                 const float* __restrict__ bias,
                                                 float* __restrict__ att) {
    int i = blockIdx.x >> 5;
    int b = blockIdx.x & 31;
    int t = threadIdx.x;
    float sv = s1[b * K_ + i];
    float4 s2v = ((const float4*)(s2 + b * K_))[t];
    float4 bv  = ((const float4*)(bias + (size_t)i * K_))[t];
    float e[4];
    {
        float v;
        v = sv + s2v.x; v = v > 0.f ? v : ALPHA_ * v; e[0] = __expf(v + bv.x);
        v = sv + s2v.y; v = v > 0.f ? v : ALPHA_ * v; e[1] = __expf(v + bv.y);
        v = sv + s2v.z; v = v > 0.f ? v : ALPHA_ * v; e[2] = __expf(v + bv.z);
        v = sv + s2v.w; v = v > 0.f ? v : ALPHA_ * v; e[3] = __expf(v + bv.w);
    }
    float sum = e[0] + e[1] + e[2] + e[3];
    for (int m = 32; m; m >>= 1) sum += __shfl_xor(sum, m, 64);
    __shared__ float reds[4];
    int wave = t >> 6, lane = t & 63;
    if (lane == 0) reds[wave] = sum;
    __syncthreads();
    sum = reds[0] + reds[1] + reds[2] + reds[3];
    float r = 1.f / sum;
    float4 o; o.x = e[0] * r; o.y = e[1] * r; o.z = e[2] * r; o.w = e[3] * r;
    ((float4*)(att + ((size_t)b * K_ + i) * K_))[t] = o;
}

// ---------------- att@x via bf16 MFMA: 32i x 128f, NO LDS, NO BARRIERS -------
// Round-9: both MFMA operands loaded per-lane directly from global.
//  * A (att): as in round 6-8 (fp32 from L3/HBM, cvt to bf16).
//  * B (xt): direct from global — xt's b-slice is 256KB (1MB/XCD with the
//    swizzle), L2-resident; a wave's fragment reads cover 16 rows x 64
//    contiguous bytes = 16 full 64B lines (fully coalesced).
//  Deletes both LDS buffers, all staging writes, and all 16 __syncthreads():
//  waves drift freely (TLP hides latency instead of intra-wave pipelining),
//  occupancy rises from the LDS/launch-bounds cap to the VGPR limit.
//  Mechanism target: round-8 showed attx is not L2-locality-bound (swizzle
//  null) — it is lockstep/latency-bound; this removes the lockstep.
__global__ __launch_bounds__(256) void k_attx(const float* __restrict__ att,
                                              const unsigned short* __restrict__ xt,
                                              const float* __restrict__ x,
                                              unsigned short* __restrict__ ht) {
    int flatb = blockIdx.y * gridDim.x + blockIdx.x;     // [0,1024)
    int swz   = (flatb & 7) * 128 + (flatb >> 3);        // XCD-chunked, bijective
    int b  = swz >> 5;
    int i0 = (swz & 31) * 32;
    int t  = threadIdx.x;
    int wave = t >> 6, lane = t & 63;
    int quad = lane >> 4, l15 = lane & 15;

    const float* ab = att + ((size_t)b * K_ + i0) * K_;
    const float* arow0 = ab + (size_t)l15 * K_ + quad * 8;
    const float* arow1 = arow0 + 16 * K_;

    // B-fragment base: xt[b][kt][row][kk], row = wave*32 + n*16 + l15
    const unsigned short* xb = xt + (size_t)b * 16 * 128 * 64
                             + ((size_t)(wave * 32 + l15)) * 64 + quad * 8;
    // n=0 at +0, n=1 at +16*64; kt stride = 128*64; kh stride = 32

    f32x4_t acc[2][2];
#pragma unroll
    for (int m = 0; m < 2; ++m)
#pragma unroll
        for (int n = 0; n < 2; ++n) acc[m][n] = (f32x4_t)(0.f);

#pragma unroll 2
    for (int kt = 0; kt < 16; ++kt) {
        int ko = kt * 64;
        const unsigned short* xk = xb + (size_t)kt * 128 * 64;
        // issue all loads for this tile first (no barriers: compiler/HW overlap)
        float4 av[2][2][2];
#pragma unroll
        for (int kh = 0; kh < 2; ++kh) {
            av[0][kh][0] = *(const float4*)(arow0 + ko + kh * 32);
            av[0][kh][1] = *(const float4*)(arow0 + ko + kh * 32 + 4);
            av[1][kh][0] = *(const float4*)(arow1 + ko + kh * 32);
            av[1][kh][1] = *(const float4*)(arow1 + ko + kh * 32 + 4);
        }
        bf16x8_t bff[2][2];
#pragma unroll
        for (int kh = 0; kh < 2; ++kh) {
            bff[kh][0] = *(const bf16x8_t*)(xk + kh * 32);
            bff[kh][1] = *(const bf16x8_t*)(xk + 16 * 64 + kh * 32);
        }
        // cvt A + MFMA
#pragma unroll
        for (int kh = 0; kh < 2; ++kh) {
            bf16x8_t af[2];
#pragma unroll
            for (int m = 0; m < 2; ++m) {
                union { __bf16 h[8]; bf16x8_t v; } p;
                float4 v0 = av[m][kh][0], v1 = av[m][kh][1];
                p.h[0] = (__bf16)v0.x; p.h[1] = (__bf16)v0.y;
                p.h[2] = (__bf16)v0.z; p.h[3] = (__bf16)v0.w;
                p.h[4] = (__bf16)v1.x; p.h[5] = (__bf16)v1.y;
                p.h[6] = (__bf16)v1.z; p.h[7] = (__bf16)v1.w;
                af[m] = p.v;
            }
#pragma unroll
            for (int m = 0; m < 2; ++m)
#pragma unroll
                for (int n = 0; n < 2; ++n)
                    acc[m][n] = __builtin_amdgcn_mfma_f32_16x16x32_bf16(af[m], bff[kh][n], acc[m][n], 0, 0, 0);
        }
    }
    // epilogue: ht[b][f][i] = bf16(acc + x residual), 8B packed along i
#pragma unroll
    for (int m = 0; m < 2; ++m) {
#pragma unroll
        for (int n = 0; n < 2; ++n) {
            int f = wave * 32 + n * 16 + l15;
            int ib = i0 + m * 16 + quad * 4;
            union { __bf16 h[4]; ushort4 v; } p;
#pragma unroll
            for (int r = 0; r < 4; ++r) {
                int i = ib + r;
                p.h[r] = (__bf16)(acc[m][n][r] + x[((size_t)b * K_ + i) * F_ + f]);
            }
            *(ushort4*)&ht[((size_t)b * F_ + f) * K_ + ib] = p.v;
        }
    }
}

// ---------------- out2 MFMA split-K: per (fh,b,ks): C[o128][f64], K=256 ------
__global__ __launch_bounds__(256) void k_out2m(const unsigned short* __restrict__ ht,
                                               const float* __restrict__ w2,
                                               float* __restrict__ part) {
    int b  = blockIdx.y;
    int f0 = blockIdx.x * 64;
    int ks = blockIdx.z;
    int t  = threadIdx.x;
    int wave = t >> 6, lane = t & 63;
    int quad = lane >> 4, l15 = lane & 15;

    __shared__ unsigned short W_s[128 * 72];   // 128o x 64k
    __shared__ unsigned short H_s[64 * 72];    // 64f  x 64k

    f32x4_t acc[8];
#pragma unroll
    for (int m = 0; m < 8; ++m) acc[m] = (f32x4_t)(0.f);

    int wo = t >> 1, wq = t & 1;               // w2: 128 rows, 2 thr/row
    int hf = t >> 2, hq = t & 3;               // ht: 64 rows, 4 thr/row

    int kt0 = ks * 4;
    for (int kt = kt0; kt < kt0 + 4; ++kt) {
        int k0 = kt * 64;
        __syncthreads();
        // W: 128o x 64k fp32 -> bf16 (guard o>=125 -> 0), native casts
        {
            union { __bf16 h[32]; uint4 v[4]; } p;
            if (wo < OUT2_) {
                const float* src = w2 + (size_t)wo * K_ + k0 + wq * 32;
#pragma unroll
                for (int q = 0; q < 8; ++q) {
                    float4 v = *(const float4*)(src + q * 4);
                    p.h[q * 4]     = (__bf16)v.x;
                    p.h[q * 4 + 1] = (__bf16)v.y;
                    p.h[q * 4 + 2] = (__bf16)v.z;
                    p.h[q * 4 + 3] = (__bf16)v.w;
                }
            } else {
#pragma unroll
                for (int q = 0; q < 4; ++q) p.v[q] = make_uint4(0, 0, 0, 0);
            }
            uint4* d = (uint4*)&W_s[wo * 72 + wq * 32];
#pragma unroll
            for (int q = 0; q < 4; ++q) d[q] = p.v[q];
        }
        // H: 64f x 64k bf16 copy (2 uint4/thread)
        {
            const uint4* src = (const uint4*)(ht + ((size_t)b * F_ + f0 + hf) * K_ + k0) + hq * 2;
            uint4* d = (uint4*)&H_s[hf * 72 + hq * 16];
            d[0] = src[0]; d[1] = src[1];
        }
        __syncthreads();
#pragma unroll
        for (int kh = 0; kh < 2; ++kh) {
            bf16x8_t bf = *(const bf16x8_t*)&H_s[(wave * 16 + l15) * 72 + kh * 32 + quad * 8];
#pragma unroll
            for (int m = 0; m < 8; ++m) {
                bf16x8_t af = *(const bf16x8_t*)&W_s[(m * 16 + l15) * 72 + kh * 32 + quad * 8];
                acc[m] = __builtin_amdgcn_mfma_f32_16x16x32_bf16(af, bf, acc[m], 0, 0, 0);
            }
        }
    }
    // partials: part[((ks*32+b)*128 + f)*128 + o], f32x4 along o
    int f = f0 + wave * 16 + l15;
    float* prow = part + ((size_t)(ks * 32 + b) * 128 + f) * 128;
#pragma unroll
    for (int m = 0; m < 8; ++m)
        *(f32x4_t*)&prow[m * 16 + quad * 4] = acc[m];
}

// ---------------- out2 epilogue: out = relu(sum_s part + b2) -----------------
__global__ __launch_bounds__(256) void k_out2e(const float* __restrict__ part,
                                               const float* __restrict__ b2,
                                               float* __restrict__ out) {
    int idx = blockIdx.x * 256 + threadIdx.x;           // over B*F*OUT2 = 512000
    if (idx >= B_ * F_ * OUT2_) return;
    int o  = idx % OUT2_;
    int bf = idx / OUT2_;                               // b*F + f, in [0, 4096)
    float v = b2[o];
#pragma unroll
    for (int s = 0; s < 4; ++s) v += part[((size_t)s * 4096 + bf) * 128 + o];
    out[idx] = v > 0.f ? v : 0.f;
}

extern "C" void kernel_launch(void* const* d_in, const int* in_sizes, int n_in,
                              void* d_out, int out_size, void* d_ws, size_t ws_size,
                              hipStream_t stream) {
    const float* x      = (const float*)d_in[0];
    const float* lin_w  = (const float*)d_in[1];
    const float* lin_b  = (const float*)d_in[2];
    const float* a      = (const float*)d_in[3];
    const float* bias   = (const float*)d_in[4];
    const float* lin2_w = (const float*)d_in[5];
    const float* lin2_b = (const float*)d_in[6];

    float* out = (float*)d_out;
    float* h2  = out;                                  // B*F*OUT2
    float* att = out + (size_t)B_ * F_ * OUT2_;        // B*K*K

    // ws: 512 (unused, layout-preserving) | s1 32K | s2 32K | ht bf16 8MB |
    // xt bf16 8MB (reused as part). total 17,041,408 B == proven footprint.
    float* ws = (float*)d_ws;
    float* s1 = ws + 512;
    float* s2 = ws + 512 + B_ * K_;
    unsigned short* ht = (unsigned short*)(ws + 512 + 2 * B_ * K_);   // B*F*K bf16
    unsigned short* xt = ht + (size_t)B_ * K_ * F_;                   // B*K*F bf16
    float* part = (float*)xt;   // 4*32*128*128 floats = 8 MB; xt dead after k_attx

    k_xts<<<dim3(16, B_), 256, 0, stream>>>(x, lin_w, lin_b, a, xt, s1, s2);
    k_softmax<<<B_ * K_, 256, 0, stream>>>(s1, s2, bias, att);
    k_attx<<<dim3(K_ / 32, B_), 256, 0, stream>>>(att, xt, x, ht);
    k_out2m<<<dim3(2, B_, 4), 256, 0, stream>>>(ht, lin2_w, part);
    k_out2e<<<(B_ * F_ * OUT2_ + 255) / 256, 256, 0, stream>>>(part, lin2_b, h2);
}

// Round 10
// 292.385 us; speedup vs baseline: 1.0198x; 1.0198x over previous
//
#include <hip/hip_runtime.h>

#define B_ 32
#define K_ 1024
#define F_ 128
#define E_ 128
#define OUT2_ 125
#define ALPHA_ 0.2f

typedef __bf16 bf16x8_t __attribute__((ext_vector_type(8)));
typedef float  f32x4_t  __attribute__((ext_vector_type(4)));

// ------- x transpose+cvt + scores + (fused) prep ----------------------------
__global__ __launch_bounds__(256) void k_xts(const float* __restrict__ x,
                                             const float* __restrict__ lin_w,
                                             const float* __restrict__ lin_b,
                                             const float* __restrict__ a,
                                             unsigned short* __restrict__ xt,
                                             float* __restrict__ s1,
                                             float* __restrict__ s2) {
    int kt = blockIdx.x;
    int b  = blockIdx.y;
    int t  = threadIdx.x;
    __shared__ float xs[64 * 132];
    __shared__ float red1[4][64], red2[4][64];
    __shared__ float wsl[260];

    // ws: waves 0-1 -> a1 path (f = t), waves 2-3 -> a2 path
    {
        int f = t & 127, sel = t >> 7;
        const float* av = a + sel * 128;
        float acc = 0.f;
#pragma unroll 8
        for (int e = 0; e < E_; ++e) acc += lin_w[e * F_ + f] * av[e];
        wsl[sel * 128 + f] = acc;
        if (t < 2) {
            const float* aw = a + t * 128;
            float c = 0.f;
#pragma unroll 8
            for (int e = 0; e < E_; ++e) c += lin_b[e] * aw[e];
            wsl[256 + t] = c;
        }
    }
    const float* xb = x + ((size_t)b * K_ + kt * 64) * F_;
#pragma unroll
    for (int q = 0; q < 8; ++q) {
        int flat = q * 256 + t;
        int kk = flat >> 5, f4 = flat & 31;
        float4 v = *(const float4*)(xb + (size_t)kk * F_ + f4 * 4);
        xs[kk * 132 + f4 * 4]     = v.x;
        xs[kk * 132 + f4 * 4 + 1] = v.y;
        xs[kk * 132 + f4 * 4 + 2] = v.z;
        xs[kk * 132 + f4 * 4 + 3] = v.w;
    }
    __syncthreads();
    // transpose-pack (bf16) — native casts
    {
        int f = t >> 1, half = t & 1;
        union { __bf16 h[32]; uint4 v[4]; } pack;
#pragma unroll
        for (int i = 0; i < 32; ++i) pack.h[i] = (__bf16)xs[(half * 32 + i) * 132 + f];
        unsigned short* dst = xt + (((size_t)(b * 16 + kt) * 128 + f) * 64 + half * 32);
        uint4* d4 = (uint4*)dst;
#pragma unroll
        for (int i = 0; i < 4; ++i) d4[i] = pack.v[i];
    }
    // scores: row r = t&63, f-segment p = t>>6 (32 f each), reduce via LDS
    {
        int r = t & 63, p = t >> 6;
        const float4* xr = (const float4*)&xs[r * 132 + p * 32];
        const float4* w1 = (const float4*)&wsl[p * 32];
        const float4* w2 = (const float4*)&wsl[128 + p * 32];
        float a1 = 0.f, a2 = 0.f;
#pragma unroll
        for (int q = 0; q < 8; ++q) {
            float4 xv = xr[q];
            float4 wa = w1[q], wb = w2[q];
            a1 += xv.x * wa.x + xv.y * wa.y + xv.z * wa.z + xv.w * wa.w;
            a2 += xv.x * wb.x + xv.y * wb.y + xv.z * wb.z + xv.w * wb.w;
        }
        red1[p][r] = a1; red2[p][r] = a2;
    }
    __syncthreads();
    if (t < 64) {
        s1[(size_t)b * K_ + kt * 64 + t] =
            red1[0][t] + red1[1][t] + red1[2][t] + red1[3][t] + wsl[256];
    } else if (t < 128) {
        int r = t - 64;
        s2[(size_t)b * K_ + kt * 64 + r] =
            red2[0][r] + red2[1][r] + red2[2][r] + red2[3][r] + wsl[257];
    }
}

// ---------------- softmax: one block per (i,b) row, no max pass --------------
__global__ __launch_bounds__(256) void k_softmax(const float* __restrict__ s1,
                                                 const float* __restrict__ s2,
                                                 const float* __restrict__ bias,
                                                 float* __restrict__ att) {
    int i = blockIdx.x >> 5;
    int b = blockIdx.x & 31;
    int t = threadIdx.x;
    float sv = s1[b * K_ + i];
    float4 s2v = ((const float4*)(s2 + b * K_))[t];
    float4 bv  = ((const float4*)(bias + (size_t)i * K_))[t];
    float e[4];
    {
        float v;
        v = sv + s2v.x; v = v > 0.f ? v : ALPHA_ * v; e[0] = __expf(v + bv.x);
        v = sv + s2v.y; v = v > 0.f ? v : ALPHA_ * v; e[1] = __expf(v + bv.y);
        v = sv + s2v.z; v = v > 0.f ? v : ALPHA_ * v; e[2] = __expf(v + bv.z);
        v = sv + s2v.w; v = v > 0.f ? v : ALPHA_ * v; e[3] = __expf(v + bv.w);
    }
    float sum = e[0] + e[1] + e[2] + e[3];
    for (int m = 32; m; m >>= 1) sum += __shfl_xor(sum, m, 64);
    __shared__ float reds[4];
    int wave = t >> 6, lane = t & 63;
    if (lane == 0) reds[wave] = sum;
    __syncthreads();
    sum = reds[0] + reds[1] + reds[2] + reds[3];
    float r = 1.f / sum;
    float4 o; o.x = e[0] * r; o.y = e[1] * r; o.z = e[2] * r; o.w = e[3] * r;
    ((float4*)(att + ((size_t)b * K_ + i) * K_))[t] = o;
}

// ---------------- att@x via bf16 MFMA: 32i x 128f, dbuf A+X in LDS -----------
// Round-10: the round-9 counters exposed the real attx bottleneck — per-lane
// A-fragment reads (16B/lane at 4KB row stride = scattered 64B granules) run
// HBM at ~1 TB/s. Fix: COALESCED cooperative A-staging (8 thr/row x 32B =
// 256B contiguous per row), cvt to bf16, swizzled LDS dbuf — same proven
// scheme as the X operand. One barrier per iteration, both operands
// register-prefetched across it.
__global__ __launch_bounds__(256, 4) void k_attx(const float* __restrict__ att,
                                                 const unsigned short* __restrict__ xt,
                                                 const float* __restrict__ x,
                                                 unsigned short* __restrict__ ht) {
    int flatb = blockIdx.y * gridDim.x + blockIdx.x;     // [0,1024)
    int swz   = (flatb & 7) * 128 + (flatb >> 3);        // XCD-chunked, bijective
    int b  = swz >> 5;
    int i0 = (swz & 31) * 32;
    int t  = threadIdx.x;
    int wave = t >> 6, lane = t & 63;
    int quad = lane >> 4, l15 = lane & 15;

    __shared__ unsigned short A_s[2][32 * 64];    // bf16, swizzled, dbuf (4KB)
    __shared__ unsigned short X_s[2][128 * 64];   // bf16, swizzled, dbuf (16KB)

    // A staging: row = t>>3 (32 rows), granule ag = t&7 (8 bf16 each)
    int ar = t >> 3, ag = t & 7;
    const float* asrc = att + ((size_t)b * K_ + i0 + ar) * K_ + ag * 8;
    const int aofs = ar * 64 + 8 * (ag ^ (ar & 7));      // swizzled LDS offset

    const uint4* xtb = (const uint4*)(xt + (size_t)b * 16 * 128 * 64);

    f32x4_t acc[2][2];
#pragma unroll
    for (int m = 0; m < 2; ++m)
#pragma unroll
        for (int n = 0; n < 2; ++n) acc[m][n] = (f32x4_t)(0.f);

    // prologue: stage A0 + X0 into buf 0
    {
        float4 a0 = *(const float4*)(asrc);
        float4 a1 = *(const float4*)(asrc + 4);
#pragma unroll
        for (int q = 0; q < 4; ++q) {
            int flat2 = q * 256 + t;
            int row = flat2 >> 3, g = flat2 & 7;
            *(uint4*)&X_s[0][row * 64 + 8 * (g ^ (row & 7))] = xtb[flat2];
        }
        union { __bf16 h[8]; uint4 v; } p;
        p.h[0] = (__bf16)a0.x; p.h[1] = (__bf16)a0.y;
        p.h[2] = (__bf16)a0.z; p.h[3] = (__bf16)a0.w;
        p.h[4] = (__bf16)a1.x; p.h[5] = (__bf16)a1.y;
        p.h[6] = (__bf16)a1.z; p.h[7] = (__bf16)a1.w;
        *(uint4*)&A_s[0][aofs] = p.v;
    }
    __syncthreads();

    int cur = 0;
#pragma unroll 2
    for (int kt = 0; kt < 16; ++kt) {
        // issue next-tile loads (A coalesced 256B/row, X lane-contiguous)
        uint4 xn[4];
        float4 an0, an1;
        if (kt < 15) {
            const uint4* src = xtb + (size_t)(kt + 1) * 1024;
#pragma unroll
            for (int q = 0; q < 4; ++q) xn[q] = src[q * 256 + t];
            const float* as2 = asrc + (kt + 1) * 64;
            an0 = *(const float4*)(as2);
            an1 = *(const float4*)(as2 + 4);
        }
        // MFMAs for tile kt from LDS[cur]
#pragma unroll
        for (int kh = 0; kh < 2; ++kh) {
            int g = (kh << 2) | quad;
            bf16x8_t af[2], bff[2];
#pragma unroll
            for (int m = 0; m < 2; ++m) {
                int row = m * 16 + l15;
                af[m] = *(const bf16x8_t*)&A_s[cur][row * 64 + 8 * (g ^ (row & 7))];
            }
#pragma unroll
            for (int n = 0; n < 2; ++n) {
                int row = wave * 32 + n * 16 + l15;
                bff[n] = *(const bf16x8_t*)&X_s[cur][row * 64 + 8 * (g ^ (row & 7))];
            }
#pragma unroll
            for (int m = 0; m < 2; ++m)
#pragma unroll
                for (int n = 0; n < 2; ++n)
                    acc[m][n] = __builtin_amdgcn_mfma_f32_16x16x32_bf16(af[m], bff[n], acc[m][n], 0, 0, 0);
        }
        // write staged tiles into buf[cur^1]
        if (kt < 15) {
            union { __bf16 h[8]; uint4 v; } p;
            p.h[0] = (__bf16)an0.x; p.h[1] = (__bf16)an0.y;
            p.h[2] = (__bf16)an0.z; p.h[3] = (__bf16)an0.w;
            p.h[4] = (__bf16)an1.x; p.h[5] = (__bf16)an1.y;
            p.h[6] = (__bf16)an1.z; p.h[7] = (__bf16)an1.w;
            *(uint4*)&A_s[cur ^ 1][aofs] = p.v;
#pragma unroll
            for (int q = 0; q < 4; ++q) {
                int flat2 = q * 256 + t;
                int row = flat2 >> 3, g = flat2 & 7;
                *(uint4*)&X_s[cur ^ 1][row * 64 + 8 * (g ^ (row & 7))] = xn[q];
            }
        }
        __syncthreads();
        cur ^= 1;
    }
    // epilogue: ht[b][f][i] = bf16(acc + x residual), 8B packed along i
#pragma unroll
    for (int m = 0; m < 2; ++m) {
#pragma unroll
        for (int n = 0; n < 2; ++n) {
            int f = wave * 32 + n * 16 + l15;
            int ib = i0 + m * 16 + quad * 4;
            union { __bf16 h[4]; ushort4 v; } p;
#pragma unroll
            for (int r = 0; r < 4; ++r) {
                int i = ib + r;
                p.h[r] = (__bf16)(acc[m][n][r] + x[((size_t)b * K_ + i) * F_ + f]);
            }
            *(ushort4*)&ht[((size_t)b * F_ + f) * K_ + ib] = p.v;
        }
    }
}

// ---------------- out2 MFMA split-K: per (fh,b,ks): C[o128][f64], K=256 ------
__global__ __launch_bounds__(256) void k_out2m(const unsigned short* __restrict__ ht,
                                               const float* __restrict__ w2,
                                               float* __restrict__ part) {
    int b  = blockIdx.y;
    int f0 = blockIdx.x * 64;
    int ks = blockIdx.z;
    int t  = threadIdx.x;
    int wave = t >> 6, lane = t & 63;
    int quad = lane >> 4, l15 = lane & 15;

    __shared__ unsigned short W_s[128 * 72];   // 128o x 64k
    __shared__ unsigned short H_s[64 * 72];    // 64f  x 64k

    f32x4_t acc[8];
#pragma unroll
    for (int m = 0; m < 8; ++m) acc[m] = (f32x4_t)(0.f);

    int wo = t >> 1, wq = t & 1;               // w2: 128 rows, 2 thr/row
    int hf = t >> 2, hq = t & 3;               // ht: 64 rows, 4 thr/row

    int kt0 = ks * 4;
    for (int kt = kt0; kt < kt0 + 4; ++kt) {
        int k0 = kt * 64;
        __syncthreads();
        // W: 128o x 64k fp32 -> bf16 (guard o>=125 -> 0), native casts
        {
            union { __bf16 h[32]; uint4 v[4]; } p;
            if (wo < OUT2_) {
                const float* src = w2 + (size_t)wo * K_ + k0 + wq * 32;
#pragma unroll
                for (int q = 0; q < 8; ++q) {
                    float4 v = *(const float4*)(src + q * 4);
                    p.h[q * 4]     = (__bf16)v.x;
                    p.h[q * 4 + 1] = (__bf16)v.y;
                    p.h[q * 4 + 2] = (__bf16)v.z;
                    p.h[q * 4 + 3] = (__bf16)v.w;
                }
            } else {
#pragma unroll
                for (int q = 0; q < 4; ++q) p.v[q] = make_uint4(0, 0, 0, 0);
            }
            uint4* d = (uint4*)&W_s[wo * 72 + wq * 32];
#pragma unroll
            for (int q = 0; q < 4; ++q) d[q] = p.v[q];
        }
        // H: 64f x 64k bf16 copy (2 uint4/thread)
        {
            const uint4* src = (const uint4*)(ht + ((size_t)b * F_ + f0 + hf) * K_ + k0) + hq * 2;
            uint4* d = (uint4*)&H_s[hf * 72 + hq * 16];
            d[0] = src[0]; d[1] = src[1];
        }
        __syncthreads();
#pragma unroll
        for (int kh = 0; kh < 2; ++kh) {
            bf16x8_t bf = *(const bf16x8_t*)&H_s[(wave * 16 + l15) * 72 + kh * 32 + quad * 8];
#pragma unroll
            for (int m = 0; m < 8; ++m) {
                bf16x8_t af = *(const bf16x8_t*)&W_s[(m * 16 + l15) * 72 + kh * 32 + quad * 8];
                acc[m] = __builtin_amdgcn_mfma_f32_16x16x32_bf16(af, bf, acc[m], 0, 0, 0);
            }
        }
    }
    // partials: part[((ks*32+b)*128 + f)*128 + o], f32x4 along o
    int f = f0 + wave * 16 + l15;
    float* prow = part + ((size_t)(ks * 32 + b) * 128 + f) * 128;
#pragma unroll
    for (int m = 0; m < 8; ++m)
        *(f32x4_t*)&prow[m * 16 + quad * 4] = acc[m];
}

// ---------------- out2 epilogue: out = relu(sum_s part + b2) -----------------
__global__ __launch_bounds__(256) void k_out2e(const float* __restrict__ part,
                                               const float* __restrict__ b2,
                                               float* __restrict__ out) {
    int idx = blockIdx.x * 256 + threadIdx.x;           // over B*F*OUT2 = 512000
    if (idx >= B_ * F_ * OUT2_) return;
    int o  = idx % OUT2_;
    int bf = idx / OUT2_;                               // b*F + f, in [0, 4096)
    float v = b2[o];
#pragma unroll
    for (int s = 0; s < 4; ++s) v += part[((size_t)s * 4096 + bf) * 128 + o];
    out[idx] = v > 0.f ? v : 0.f;
}

extern "C" void kernel_launch(void* const* d_in, const int* in_sizes, int n_in,
                              void* d_out, int out_size, void* d_ws, size_t ws_size,
                              hipStream_t stream) {
    const float* x      = (const float*)d_in[0];
    const float* lin_w  = (const float*)d_in[1];
    const float* lin_b  = (const float*)d_in[2];
    const float* a      = (const float*)d_in[3];
    const float* bias   = (const float*)d_in[4];
    const float* lin2_w = (const float*)d_in[5];
    const float* lin2_b = (const float*)d_in[6];

    float* out = (float*)d_out;
    float* h2  = out;                                  // B*F*OUT2
    float* att = out + (size_t)B_ * F_ * OUT2_;        // B*K*K

    // ws: 512 (unused, layout-preserving) | s1 32K | s2 32K | ht bf16 8MB |
    // xt bf16 8MB (reused as part). total 17,041,408 B == proven footprint.
    float* ws = (float*)d_ws;
    float* s1 = ws + 512;
    float* s2 = ws + 512 + B_ * K_;
    unsigned short* ht = (unsigned short*)(ws + 512 + 2 * B_ * K_);   // B*F*K bf16
    unsigned short* xt = ht + (size_t)B_ * K_ * F_;                   // B*K*F bf16
    float* part = (float*)xt;   // 4*32*128*128 floats = 8 MB; xt dead after k_attx

    k_xts<<<dim3(16, B_), 256, 0, stream>>>(x, lin_w, lin_b, a, xt, s1, s2);
    k_softmax<<<B_ * K_, 256, 0, stream>>>(s1, s2, bias, att);
    k_attx<<<dim3(K_ / 32, B_), 256, 0, stream>>>(att, xt, x, ht);
    k_out2m<<<dim3(2, B_, 4), 256, 0, stream>>>(ht, lin2_w, part);
    k_out2e<<<(B_ * F_ * OUT2_ + 255) / 256, 256, 0, stream>>>(part, lin2_b, h2);
}

// Round 11
// 250.268 us; speedup vs baseline: 1.1914x; 1.1683x over previous
//
#include <hip/hip_runtime.h>

#define B_ 32
#define K_ 1024
#define F_ 128
#define E_ 128
#define OUT2_ 125
#define ALPHA_ 0.2f

typedef __bf16 bf16x8_t __attribute__((ext_vector_type(8)));
typedef float  f32x4_t  __attribute__((ext_vector_type(4)));

// ------- x transpose+cvt + scores + (fused) prep ----------------------------
__global__ __launch_bounds__(256) void k_xts(const float* __restrict__ x,
                                             const float* __restrict__ lin_w,
                                             const float* __restrict__ lin_b,
                                             const float* __restrict__ a,
                                             unsigned short* __restrict__ xt,
                                             float* __restrict__ s1,
                                             float* __restrict__ s2) {
    int kt = blockIdx.x;
    int b  = blockIdx.y;
    int t  = threadIdx.x;
    __shared__ float xs[64 * 132];
    __shared__ float red1[4][64], red2[4][64];
    __shared__ float wsl[260];

    // ws: waves 0-1 -> a1 path (f = t), waves 2-3 -> a2 path
    {
        int f = t & 127, sel = t >> 7;
        const float* av = a + sel * 128;
        float acc = 0.f;
#pragma unroll 8
        for (int e = 0; e < E_; ++e) acc += lin_w[e * F_ + f] * av[e];
        wsl[sel * 128 + f] = acc;
        if (t < 2) {
            const float* aw = a + t * 128;
            float c = 0.f;
#pragma unroll 8
            for (int e = 0; e < E_; ++e) c += lin_b[e] * aw[e];
            wsl[256 + t] = c;
        }
    }
    const float* xb = x + ((size_t)b * K_ + kt * 64) * F_;
#pragma unroll
    for (int q = 0; q < 8; ++q) {
        int flat = q * 256 + t;
        int kk = flat >> 5, f4 = flat & 31;
        float4 v = *(const float4*)(xb + (size_t)kk * F_ + f4 * 4);
        xs[kk * 132 + f4 * 4]     = v.x;
        xs[kk * 132 + f4 * 4 + 1] = v.y;
        xs[kk * 132 + f4 * 4 + 2] = v.z;
        xs[kk * 132 + f4 * 4 + 3] = v.w;
    }
    __syncthreads();
    // transpose-pack (bf16) — native casts
    {
        int f = t >> 1, half = t & 1;
        union { __bf16 h[32]; uint4 v[4]; } pack;
#pragma unroll
        for (int i = 0; i < 32; ++i) pack.h[i] = (__bf16)xs[(half * 32 + i) * 132 + f];
        unsigned short* dst = xt + (((size_t)(b * 16 + kt) * 128 + f) * 64 + half * 32);
        uint4* d4 = (uint4*)dst;
#pragma unroll
        for (int i = 0; i < 4; ++i) d4[i] = pack.v[i];
    }
    // scores: row r = t&63, f-segment p = t>>6 (32 f each), reduce via LDS
    {
        int r = t & 63, p = t >> 6;
        const float4* xr = (const float4*)&xs[r * 132 + p * 32];
        const float4* w1 = (const float4*)&wsl[p * 32];
        const float4* w2 = (const float4*)&wsl[128 + p * 32];
        float a1 = 0.f, a2 = 0.f;
#pragma unroll
        for (int q = 0; q < 8; ++q) {
            float4 xv = xr[q];
            float4 wa = w1[q], wb = w2[q];
            a1 += xv.x * wa.x + xv.y * wa.y + xv.z * wa.z + xv.w * wa.w;
            a2 += xv.x * wb.x + xv.y * wb.y + xv.z * wb.z + xv.w * wb.w;
        }
        red1[p][r] = a1; red2[p][r] = a2;
    }
    __syncthreads();
    if (t < 64) {
        s1[(size_t)b * K_ + kt * 64 + t] =
            red1[0][t] + red1[1][t] + red1[2][t] + red1[3][t] + wsl[256];
    } else if (t < 128) {
        int r = t - 64;
        s2[(size_t)b * K_ + kt * 64 + r] =
            red2[0][r] + red2[1][r] + red2[2][r] + red2[3][r] + wsl[257];
    }
}

// ---------------- softmax: one block per (i,b) row, no max pass --------------
__global__ __launch_bounds__(256) void k_softmax(const float* __restrict__ s1,
                                                 const float* __restrict__ s2,
                                                 const float* __restrict__ bias,
                                                 float* __restrict__ att) {
    int i = blockIdx.x >> 5;
    int b = blockIdx.x & 31;
    int t = threadIdx.x;
    float sv = s1[b * K_ + i];
    float4 s2v = ((const float4*)(s2 + b * K_))[t];
    float4 bv  = ((const float4*)(bias + (size_t)i * K_))[t];
    float e[4];
    {
        float v;
        v = sv + s2v.x; v = v > 0.f ? v : ALPHA_ * v; e[0] = __expf(v + bv.x);
        v = sv + s2v.y; v = v > 0.f ? v : ALPHA_ * v; e[1] = __expf(v + bv.y);
        v = sv + s2v.z; v = v > 0.f ? v : ALPHA_ * v; e[2] = __expf(v + bv.z);
        v = sv + s2v.w; v = v > 0.f ? v : ALPHA_ * v; e[3] = __expf(v + bv.w);
    }
    float sum = e[0] + e[1] + e[2] + e[3];
    for (int m = 32; m; m >>= 1) sum += __shfl_xor(sum, m, 64);
    __shared__ float reds[4];
    int wave = t >> 6, lane = t & 63;
    if (lane == 0) reds[wave] = sum;
    __syncthreads();
    sum = reds[0] + reds[1] + reds[2] + reds[3];
    float r = 1.f / sum;
    float4 o; o.x = e[0] * r; o.y = e[1] * r; o.z = e[2] * r; o.w = e[3] * r;
    ((float4*)(att + ((size_t)b * K_ + i) * K_))[t] = o;
}

// ---------------- att@x via bf16 MFMA: A in LDS dbuf, X direct from L2 -------
// Round-11: combine the proven halves of rounds 9 & 10.
//  * A (att, the HBM stream): cooperatively staged, 256B-contiguous rows
//    (round-10 fix — per-lane A reads were scattered 64B granules @ ~1TB/s).
//  * X (xt, L2-resident): per-lane direct fragment loads — round 9 showed
//    this pattern is fully coalesced (16x64B lines/wave) and L2-hit
//    (FETCH there was att-only). No X LDS, no X staging.
//  LDS drops 40KB -> 8KB; __launch_bounds__(256,8) caps VGPR at 64 ->
//  8 blocks/CU = 8 waves/SIMD, doubling the latency-hiding pool the round-10
//  counters showed was too shallow (MfmaUtil 3.7 / VALUBusy 3.4 / all idle).
__global__ __launch_bounds__(256, 8) void k_attx(const float* __restrict__ att,
                                                 const unsigned short* __restrict__ xt,
                                                 const float* __restrict__ x,
                                                 unsigned short* __restrict__ ht) {
    int flatb = blockIdx.y * gridDim.x + blockIdx.x;     // [0,1024)
    int swz   = (flatb & 7) * 128 + (flatb >> 3);        // XCD-chunked, bijective
    int b  = swz >> 5;
    int i0 = (swz & 31) * 32;
    int t  = threadIdx.x;
    int wave = t >> 6, lane = t & 63;
    int quad = lane >> 4, l15 = lane & 15;

    __shared__ unsigned short A_s[2][32 * 64];    // bf16, swizzled, dbuf (8KB)

    // A staging: row = t>>3 (32 rows), granule ag = t&7 (8 bf16 each)
    int ar = t >> 3, ag = t & 7;
    const float* asrc = att + ((size_t)b * K_ + i0 + ar) * K_ + ag * 8;
    const int aofs = ar * 64 + 8 * (ag ^ (ar & 7));      // swizzled LDS offset

    // X direct per-lane base: xt[b][kt][row][kk], row = wave*32 + n*16 + l15
    const unsigned short* xb = xt + (size_t)b * 16 * 128 * 64
                             + ((size_t)(wave * 32 + l15)) * 64 + quad * 8;

    f32x4_t acc[2][2];
#pragma unroll
    for (int m = 0; m < 2; ++m)
#pragma unroll
        for (int n = 0; n < 2; ++n) acc[m][n] = (f32x4_t)(0.f);

    // prologue: stage A0 into buf 0
    {
        float4 a0 = *(const float4*)(asrc);
        float4 a1 = *(const float4*)(asrc + 4);
        union { __bf16 h[8]; uint4 v; } p;
        p.h[0] = (__bf16)a0.x; p.h[1] = (__bf16)a0.y;
        p.h[2] = (__bf16)a0.z; p.h[3] = (__bf16)a0.w;
        p.h[4] = (__bf16)a1.x; p.h[5] = (__bf16)a1.y;
        p.h[6] = (__bf16)a1.z; p.h[7] = (__bf16)a1.w;
        *(uint4*)&A_s[0][aofs] = p.v;
    }
    __syncthreads();

#pragma unroll 2
    for (int kt = 0; kt < 16; ++kt) {
        int cur = kt & 1;
        const unsigned short* xk = xb + (size_t)kt * 128 * 64;
        // issue next A tile loads (coalesced 256B/row) + this tile's X loads
        float4 an0, an1;
        if (kt < 15) {
            const float* as2 = asrc + (kt + 1) * 64;
            an0 = *(const float4*)(as2);
            an1 = *(const float4*)(as2 + 4);
        }
        bf16x8_t bff[2][2];
#pragma unroll
        for (int kh = 0; kh < 2; ++kh) {
            bff[kh][0] = *(const bf16x8_t*)(xk + kh * 32);
            bff[kh][1] = *(const bf16x8_t*)(xk + 16 * 64 + kh * 32);
        }
        // MFMAs for tile kt: A from LDS[cur], X from registers
#pragma unroll
        for (int kh = 0; kh < 2; ++kh) {
            int g = (kh << 2) | quad;
            bf16x8_t af[2];
#pragma unroll
            for (int m = 0; m < 2; ++m) {
                int row = m * 16 + l15;
                af[m] = *(const bf16x8_t*)&A_s[cur][row * 64 + 8 * (g ^ (row & 7))];
            }
#pragma unroll
            for (int m = 0; m < 2; ++m)
#pragma unroll
                for (int n = 0; n < 2; ++n)
                    acc[m][n] = __builtin_amdgcn_mfma_f32_16x16x32_bf16(af[m], bff[kh][n], acc[m][n], 0, 0, 0);
        }
        // stage next A into buf[cur^1]
        if (kt < 15) {
            union { __bf16 h[8]; uint4 v; } p;
            p.h[0] = (__bf16)an0.x; p.h[1] = (__bf16)an0.y;
            p.h[2] = (__bf16)an0.z; p.h[3] = (__bf16)an0.w;
            p.h[4] = (__bf16)an1.x; p.h[5] = (__bf16)an1.y;
            p.h[6] = (__bf16)an1.z; p.h[7] = (__bf16)an1.w;
            *(uint4*)&A_s[cur ^ 1][aofs] = p.v;
        }
        __syncthreads();
    }
    // epilogue: ht[b][f][i] = bf16(acc + x residual), 8B packed along i
#pragma unroll
    for (int m = 0; m < 2; ++m) {
#pragma unroll
        for (int n = 0; n < 2; ++n) {
            int f = wave * 32 + n * 16 + l15;
            int ib = i0 + m * 16 + quad * 4;
            union { __bf16 h[4]; ushort4 v; } p;
#pragma unroll
            for (int r = 0; r < 4; ++r) {
                int i = ib + r;
                p.h[r] = (__bf16)(acc[m][n][r] + x[((size_t)b * K_ + i) * F_ + f]);
            }
            *(ushort4*)&ht[((size_t)b * F_ + f) * K_ + ib] = p.v;
        }
    }
}

// ---------------- out2 MFMA split-K: per (fh,b,ks): C[o128][f64], K=256 ------
__global__ __launch_bounds__(256) void k_out2m(const unsigned short* __restrict__ ht,
                                               const float* __restrict__ w2,
                                               float* __restrict__ part) {
    int b  = blockIdx.y;
    int f0 = blockIdx.x * 64;
    int ks = blockIdx.z;
    int t  = threadIdx.x;
    int wave = t >> 6, lane = t & 63;
    int quad = lane >> 4, l15 = lane & 15;

    __shared__ unsigned short W_s[128 * 72];   // 128o x 64k
    __shared__ unsigned short H_s[64 * 72];    // 64f  x 64k

    f32x4_t acc[8];
#pragma unroll
    for (int m = 0; m < 8; ++m) acc[m] = (f32x4_t)(0.f);

    int wo = t >> 1, wq = t & 1;               // w2: 128 rows, 2 thr/row
    int hf = t >> 2, hq = t & 3;               // ht: 64 rows, 4 thr/row

    int kt0 = ks * 4;
    for (int kt = kt0; kt < kt0 + 4; ++kt) {
        int k0 = kt * 64;
        __syncthreads();
        // W: 128o x 64k fp32 -> bf16 (guard o>=125 -> 0), native casts
        {
            union { __bf16 h[32]; uint4 v[4]; } p;
            if (wo < OUT2_) {
                const float* src = w2 + (size_t)wo * K_ + k0 + wq * 32;
#pragma unroll
                for (int q = 0; q < 8; ++q) {
                    float4 v = *(const float4*)(src + q * 4);
                    p.h[q * 4]     = (__bf16)v.x;
                    p.h[q * 4 + 1] = (__bf16)v.y;
                    p.h[q * 4 + 2] = (__bf16)v.z;
                    p.h[q * 4 + 3] = (__bf16)v.w;
                }
            } else {
#pragma unroll
                for (int q = 0; q < 4; ++q) p.v[q] = make_uint4(0, 0, 0, 0);
            }
            uint4* d = (uint4*)&W_s[wo * 72 + wq * 32];
#pragma unroll
            for (int q = 0; q < 4; ++q) d[q] = p.v[q];
        }
        // H: 64f x 64k bf16 copy (2 uint4/thread)
        {
            const uint4* src = (const uint4*)(ht + ((size_t)b * F_ + f0 + hf) * K_ + k0) + hq * 2;
            uint4* d = (uint4*)&H_s[hf * 72 + hq * 16];
            d[0] = src[0]; d[1] = src[1];
        }
        __syncthreads();
#pragma unroll
        for (int kh = 0; kh < 2; ++kh) {
            bf16x8_t bf = *(const bf16x8_t*)&H_s[(wave * 16 + l15) * 72 + kh * 32 + quad * 8];
#pragma unroll
            for (int m = 0; m < 8; ++m) {
                bf16x8_t af = *(const bf16x8_t*)&W_s[(m * 16 + l15) * 72 + kh * 32 + quad * 8];
                acc[m] = __builtin_amdgcn_mfma_f32_16x16x32_bf16(af, bf, acc[m], 0, 0, 0);
            }
        }
    }
    // partials: part[((ks*32+b)*128 + f)*128 + o], f32x4 along o
    int f = f0 + wave * 16 + l15;
    float* prow = part + ((size_t)(ks * 32 + b) * 128 + f) * 128;
#pragma unroll
    for (int m = 0; m < 8; ++m)
        *(f32x4_t*)&prow[m * 16 + quad * 4] = acc[m];
}

// ---------------- out2 epilogue: out = relu(sum_s part + b2) -----------------
__global__ __launch_bounds__(256) void k_out2e(const float* __restrict__ part,
                                               const float* __restrict__ b2,
                                               float* __restrict__ out) {
    int idx = blockIdx.x * 256 + threadIdx.x;           // over B*F*OUT2 = 512000
    if (idx >= B_ * F_ * OUT2_) return;
    int o  = idx % OUT2_;
    int bf = idx / OUT2_;                               // b*F + f, in [0, 4096)
    float v = b2[o];
#pragma unroll
    for (int s = 0; s < 4; ++s) v += part[((size_t)s * 4096 + bf) * 128 + o];
    out[idx] = v > 0.f ? v : 0.f;
}

extern "C" void kernel_launch(void* const* d_in, const int* in_sizes, int n_in,
                              void* d_out, int out_size, void* d_ws, size_t ws_size,
                              hipStream_t stream) {
    const float* x      = (const float*)d_in[0];
    const float* lin_w  = (const float*)d_in[1];
    const float* lin_b  = (const float*)d_in[2];
    const float* a      = (const float*)d_in[3];
    const float* bias   = (const float*)d_in[4];
    const float* lin2_w = (const float*)d_in[5];
    const float* lin2_b = (const float*)d_in[6];

    float* out = (float*)d_out;
    float* h2  = out;                                  // B*F*OUT2
    float* att = out + (size_t)B_ * F_ * OUT2_;        // B*K*K

    // ws: 512 (unused, layout-preserving) | s1 32K | s2 32K | ht bf16 8MB |
    // xt bf16 8MB (reused as part). total 17,041,408 B == proven footprint.
    float* ws = (float*)d_ws;
    float* s1 = ws + 512;
    float* s2 = ws + 512 + B_ * K_;
    unsigned short* ht = (unsigned short*)(ws + 512 + 2 * B_ * K_);   // B*F*K bf16
    unsigned short* xt = ht + (size_t)B_ * K_ * F_;                   // B*K*F bf16
    float* part = (float*)xt;   // 4*32*128*128 floats = 8 MB; xt dead after k_attx

    k_xts<<<dim3(16, B_), 256, 0, stream>>>(x, lin_w, lin_b, a, xt, s1, s2);
    k_softmax<<<B_ * K_, 256, 0, stream>>>(s1, s2, bias, att);
    k_attx<<<dim3(K_ / 32, B_), 256, 0, stream>>>(att, xt, x, ht);
    k_out2m<<<dim3(2, B_, 4), 256, 0, stream>>>(ht, lin2_w, part);
    k_out2e<<<(B_ * F_ * OUT2_ + 255) / 256, 256, 0, stream>>>(part, lin2_b, h2);
}